// Round 2
// baseline (890.032 us; speedup 1.0000x reference)
//
#include <hip/hip_runtime.h>
#include <stdint.h>

#define NV 16384
#define DH 64

typedef __attribute__((ext_vector_type(4))) float f32x4;
typedef __attribute__((ext_vector_type(8))) short s16x8;

static __device__ __forceinline__ unsigned short f2bf(float f) {
  union { float f; unsigned u; } x; x.f = f;
  unsigned r = x.u + 0x7fffu + ((x.u >> 16) & 1u);
  return (unsigned short)(r >> 16);
}

static __device__ __forceinline__ s16x8 cvt8(f32x4 a, f32x4 b) {
  s16x8 r;
  r[0] = (short)f2bf(a[0]); r[1] = (short)f2bf(a[1]);
  r[2] = (short)f2bf(a[2]); r[3] = (short)f2bf(a[3]);
  r[4] = (short)f2bf(b[0]); r[5] = (short)f2bf(b[1]);
  r[6] = (short)f2bf(b[2]); r[7] = (short)f2bf(b[3]);
  return r;
}

// prep: Z[i][c] = (h@W1)[i][c] fp32 ; Bt[c][i] = bf16((h@L1)[i][c])
__global__ __launch_bounds__(256) void k_prep(
    const float* __restrict__ h, const float* __restrict__ W1,
    const float* __restrict__ L1, float* __restrict__ Z,
    unsigned short* __restrict__ Bt) {
  __shared__ float Ws[4096], Ls[4096], hs[16 * 64];
  int tid = threadIdx.x;
  for (int i = tid; i < 4096; i += 256) { Ws[i] = W1[i]; Ls[i] = L1[i]; }
  int r = tid >> 6, c = tid & 63;
  int i0 = blockIdx.x << 4;
  #pragma unroll
  for (int m = 0; m < 4; ++m)
    hs[(r + 4 * m) * 64 + c] = h[(size_t)(i0 + r + 4 * m) * 64 + c];
  __syncthreads();
  float a1[4] = {0.f, 0.f, 0.f, 0.f};
  float a2[4] = {0.f, 0.f, 0.f, 0.f};
  #pragma unroll 8
  for (int k = 0; k < 64; ++k) {
    float wv = Ws[k * 64 + c];
    float lv = Ls[k * 64 + c];
    #pragma unroll
    for (int m = 0; m < 4; ++m) {
      float hv = hs[(r + 4 * m) * 64 + k];
      a1[m] += hv * wv;
      a2[m] += hv * lv;
    }
  }
  #pragma unroll
  for (int m = 0; m < 4; ++m) {
    int i = i0 + r + 4 * m;
    Z[(size_t)i * 64 + c] = a1[m];
    Bt[(size_t)c * NV + i] = f2bf(a2[m]);
  }
}

// big: Z += adj @ B  (Bt = B^T, bf16 [64][NV]); K-split over blockIdx.y, atomicAdd.
// adj loads are non-temporal (streaming, zero reuse -> don't evict Bt from L2).
// Per-wave K rotation decorrelates the column phase across the grid (all rows
// are 64KB-aligned, so lockstep column sweeps hotspot HBM channels).
__global__ __launch_bounds__(256, 4) void k_adj(
    const float* __restrict__ adj, const unsigned short* __restrict__ Bt,
    float* __restrict__ Z) {
  int lane = threadIdx.x & 63;
  int w = threadIdx.x >> 6;
  int l15 = lane & 15;
  int koff = (lane >> 4) << 3;
  int row = (blockIdx.x << 6) + (w << 4) + l15;
  int k0 = blockIdx.y << 12;  // 4096 per split
  const float* ap = adj + (size_t)row * NV + k0 + koff;
  const unsigned short* bp0 = Bt + (size_t)l15 * NV + k0 + koff;
  const unsigned short* bp1 = bp0 + (size_t)16 * NV;
  const unsigned short* bp2 = bp0 + (size_t)32 * NV;
  const unsigned short* bp3 = bp0 + (size_t)48 * NV;

  int rot = (blockIdx.x * 13 + blockIdx.y * 37 + w * 7) & 127;

  f32x4 acc0 = {0.f, 0.f, 0.f, 0.f};
  f32x4 acc1 = {0.f, 0.f, 0.f, 0.f};
  f32x4 acc2 = {0.f, 0.f, 0.f, 0.f};
  f32x4 acc3 = {0.f, 0.f, 0.f, 0.f};

  int c0 = rot << 5;
  f32x4 ca0 = __builtin_nontemporal_load((const f32x4*)(ap + c0));
  f32x4 ca1 = __builtin_nontemporal_load((const f32x4*)(ap + c0 + 4));
  s16x8 cb0 = *(const s16x8*)(bp0 + c0);
  s16x8 cb1 = *(const s16x8*)(bp1 + c0);
  s16x8 cb2 = *(const s16x8*)(bp2 + c0);
  s16x8 cb3 = *(const s16x8*)(bp3 + c0);

  for (int s = 0; s < 127; ++s) {
    int cn = ((s + 1 + rot) & 127) << 5;
    f32x4 na0 = __builtin_nontemporal_load((const f32x4*)(ap + cn));
    f32x4 na1 = __builtin_nontemporal_load((const f32x4*)(ap + cn + 4));
    s16x8 nb0 = *(const s16x8*)(bp0 + cn);
    s16x8 nb1 = *(const s16x8*)(bp1 + cn);
    s16x8 nb2 = *(const s16x8*)(bp2 + cn);
    s16x8 nb3 = *(const s16x8*)(bp3 + cn);

    s16x8 af = cvt8(ca0, ca1);
    acc0 = __builtin_amdgcn_mfma_f32_16x16x32_bf16(af, cb0, acc0, 0, 0, 0);
    acc1 = __builtin_amdgcn_mfma_f32_16x16x32_bf16(af, cb1, acc1, 0, 0, 0);
    acc2 = __builtin_amdgcn_mfma_f32_16x16x32_bf16(af, cb2, acc2, 0, 0, 0);
    acc3 = __builtin_amdgcn_mfma_f32_16x16x32_bf16(af, cb3, acc3, 0, 0, 0);

    ca0 = na0; ca1 = na1;
    cb0 = nb0; cb1 = nb1; cb2 = nb2; cb3 = nb3;
  }
  {
    s16x8 af = cvt8(ca0, ca1);
    acc0 = __builtin_amdgcn_mfma_f32_16x16x32_bf16(af, cb0, acc0, 0, 0, 0);
    acc1 = __builtin_amdgcn_mfma_f32_16x16x32_bf16(af, cb1, acc1, 0, 0, 0);
    acc2 = __builtin_amdgcn_mfma_f32_16x16x32_bf16(af, cb2, acc2, 0, 0, 0);
    acc3 = __builtin_amdgcn_mfma_f32_16x16x32_bf16(af, cb3, acc3, 0, 0, 0);
  }

  // D layout: col = lane&15 (+16*f), row = (lane>>4)*4 + reg  [m89-verified]
  int zr = (blockIdx.x << 6) + (w << 4) + ((lane >> 4) << 2);
  float* zp = Z + (size_t)zr * 64 + l15;
  #pragma unroll
  for (int r = 0; r < 4; ++r) {
    atomicAdd(zp + (size_t)r * 64 + 0, acc0[r]);
    atomicAdd(zp + (size_t)r * 64 + 16, acc1[r]);
    atomicAdd(zp + (size_t)r * 64 + 32, acc2[r]);
    atomicAdd(zp + (size_t)r * 64 + 48, acc3[r]);
  }
}

// mid epilogue: x = relu(Z*rw1[reg]+rb1[reg]); Z = x@W2 (in-place); Bt = (x@L2)^T bf16
__global__ __launch_bounds__(256) void k_mid(
    float* __restrict__ Z, const int* __restrict__ reg,
    const float* __restrict__ rw1, const float* __restrict__ rb1,
    const float* __restrict__ W2, const float* __restrict__ L2,
    unsigned short* __restrict__ Bt) {
  __shared__ float Ws[4096], Ls[4096], xs[16 * 64];
  int tid = threadIdx.x;
  for (int i = tid; i < 4096; i += 256) { Ws[i] = W2[i]; Ls[i] = L2[i]; }
  int r = tid >> 6, c = tid & 63;
  int i0 = blockIdx.x << 4;
  #pragma unroll
  for (int m = 0; m < 4; ++m) {
    int i = i0 + r + 4 * m;
    int ri = reg[i];
    float z = Z[(size_t)i * 64 + c];
    float x = z * rw1[ri * 64 + c] + rb1[ri * 64 + c];
    xs[(r + 4 * m) * 64 + c] = fmaxf(x, 0.f);
  }
  __syncthreads();
  float a1[4] = {0.f, 0.f, 0.f, 0.f};
  float a2[4] = {0.f, 0.f, 0.f, 0.f};
  #pragma unroll 8
  for (int k = 0; k < 64; ++k) {
    float wv = Ws[k * 64 + c];
    float lv = Ls[k * 64 + c];
    #pragma unroll
    for (int m = 0; m < 4; ++m) {
      float xv = xs[(r + 4 * m) * 64 + k];
      a1[m] += xv * wv;
      a2[m] += xv * lv;
    }
  }
  #pragma unroll
  for (int m = 0; m < 4; ++m) {
    int i = i0 + r + 4 * m;
    Z[(size_t)i * 64 + c] = a1[m];
    Bt[(size_t)c * NV + i] = f2bf(a2[m]);
  }
}

// out epilogue: x2 = relu(Z*rw2[reg]+rb2[reg]); out = x2 @ Wout^T + bout
__global__ __launch_bounds__(256) void k_out(
    const float* __restrict__ Z, const int* __restrict__ reg,
    const float* __restrict__ rw2, const float* __restrict__ rb2,
    const float* __restrict__ Wout, const float* __restrict__ bout,
    float* __restrict__ out) {
  __shared__ float xs[16 * 64];
  int tid = threadIdx.x;
  int r = tid >> 6, c = tid & 63;
  int i0 = blockIdx.x << 4;
  #pragma unroll
  for (int m = 0; m < 4; ++m) {
    int i = i0 + r + 4 * m;
    int ri = reg[i];
    float z = Z[(size_t)i * 64 + c];
    float x = z * rw2[ri * 64 + c] + rb2[ri * 64 + c];
    xs[(r + 4 * m) * 64 + c] = fmaxf(x, 0.f);
  }
  __syncthreads();
  if (c < 8) {
    #pragma unroll
    for (int m = 0; m < 4; ++m) {
      int i = i0 + r + 4 * m;
      float a = bout[c];
      #pragma unroll 8
      for (int k = 0; k < 64; ++k) a += xs[(r + 4 * m) * 64 + k] * Wout[c * 64 + k];
      out[(size_t)i * 8 + c] = a;
    }
  }
}

extern "C" void kernel_launch(void* const* d_in, const int* in_sizes, int n_in,
                              void* d_out, int out_size, void* d_ws, size_t ws_size,
                              hipStream_t stream) {
  const float* h    = (const float*)d_in[0];
  const float* adj  = (const float*)d_in[1];
  const int*   reg  = (const int*)d_in[2];
  const float* W1   = (const float*)d_in[3];
  const float* L1   = (const float*)d_in[4];
  const float* rw1  = (const float*)d_in[5];
  const float* rb1  = (const float*)d_in[6];
  const float* W2   = (const float*)d_in[7];
  const float* L2   = (const float*)d_in[8];
  const float* rw2  = (const float*)d_in[9];
  const float* rb2  = (const float*)d_in[10];
  const float* Wout = (const float*)d_in[11];
  const float* bout = (const float*)d_in[12];
  float* out = (float*)d_out;

  float* Z = (float*)d_ws;                                      // 4 MB
  unsigned short* Bt = (unsigned short*)((char*)d_ws + (size_t)NV * DH * 4);  // 2 MB

  k_prep<<<NV / 16, 256, 0, stream>>>(h, W1, L1, Z, Bt);
  k_adj<<<dim3(NV / 64, 4), 256, 0, stream>>>(adj, Bt, Z);
  k_mid<<<NV / 16, 256, 0, stream>>>(Z, reg, rw1, rb1, W2, L2, Bt);
  k_adj<<<dim3(NV / 64, 4), 256, 0, stream>>>(adj, Bt, Z);
  k_out<<<NV / 16, 256, 0, stream>>>(Z, reg, rw2, rb2, Wout, bout, out);
}

// Round 3
// 796.029 us; speedup vs baseline: 1.1181x; 1.1181x over previous
//
#include <hip/hip_runtime.h>
#include <stdint.h>

#define NV 16384
#define DH 64
#define BTS (NV + 64)  // padded Bt row stride: breaks 32KB power-of-2 set aliasing

typedef __attribute__((ext_vector_type(4))) float f32x4;
typedef __attribute__((ext_vector_type(8))) short s16x8;

static __device__ __forceinline__ unsigned short f2bf(float f) {
  union { float f; unsigned u; } x; x.f = f;
  unsigned r = x.u + 0x7fffu + ((x.u >> 16) & 1u);
  return (unsigned short)(r >> 16);
}

static __device__ __forceinline__ s16x8 cvt8(f32x4 a, f32x4 b) {
  s16x8 r;
  r[0] = (short)f2bf(a[0]); r[1] = (short)f2bf(a[1]);
  r[2] = (short)f2bf(a[2]); r[3] = (short)f2bf(a[3]);
  r[4] = (short)f2bf(b[0]); r[5] = (short)f2bf(b[1]);
  r[6] = (short)f2bf(b[2]); r[7] = (short)f2bf(b[3]);
  return r;
}

// prep: Z[i][c] = (h@W1)[i][c] fp32 ; Bt[c][i] = bf16((h@L1)[i][c])
__global__ __launch_bounds__(256) void k_prep(
    const float* __restrict__ h, const float* __restrict__ W1,
    const float* __restrict__ L1, float* __restrict__ Z,
    unsigned short* __restrict__ Bt) {
  __shared__ float Ws[4096], Ls[4096], hs[16 * 64];
  int tid = threadIdx.x;
  for (int i = tid; i < 4096; i += 256) { Ws[i] = W1[i]; Ls[i] = L1[i]; }
  int r = tid >> 6, c = tid & 63;
  int i0 = blockIdx.x << 4;
  #pragma unroll
  for (int m = 0; m < 4; ++m)
    hs[(r + 4 * m) * 64 + c] = h[(size_t)(i0 + r + 4 * m) * 64 + c];
  __syncthreads();
  float a1[4] = {0.f, 0.f, 0.f, 0.f};
  float a2[4] = {0.f, 0.f, 0.f, 0.f};
  #pragma unroll 8
  for (int k = 0; k < 64; ++k) {
    float wv = Ws[k * 64 + c];
    float lv = Ls[k * 64 + c];
    #pragma unroll
    for (int m = 0; m < 4; ++m) {
      float hv = hs[(r + 4 * m) * 64 + k];
      a1[m] += hv * wv;
      a2[m] += hv * lv;
    }
  }
  #pragma unroll
  for (int m = 0; m < 4; ++m) {
    int i = i0 + r + 4 * m;
    Z[(size_t)i * 64 + c] = a1[m];
    Bt[(size_t)c * BTS + i] = f2bf(a2[m]);
  }
}

// big: Z += adj @ B  (Bt = B^T, bf16 [64][BTS]); K-split over blockIdx.y, atomicAdd.
__global__ __launch_bounds__(256, 4) void k_adj(
    const float* __restrict__ adj, const unsigned short* __restrict__ Bt,
    float* __restrict__ Z) {
  int lane = threadIdx.x & 63;
  int w = threadIdx.x >> 6;
  int l15 = lane & 15;
  int koff = (lane >> 4) << 3;
  int row = (blockIdx.x << 6) + (w << 4) + l15;
  int k0 = blockIdx.y << 12;  // 4096 per split
  const float* ap = adj + (size_t)row * NV + k0 + koff;
  const unsigned short* bp0 = Bt + (size_t)l15 * BTS + k0 + koff;
  const unsigned short* bp1 = bp0 + (size_t)16 * BTS;
  const unsigned short* bp2 = bp0 + (size_t)32 * BTS;
  const unsigned short* bp3 = bp0 + (size_t)48 * BTS;

  f32x4 acc0 = {0.f, 0.f, 0.f, 0.f};
  f32x4 acc1 = {0.f, 0.f, 0.f, 0.f};
  f32x4 acc2 = {0.f, 0.f, 0.f, 0.f};
  f32x4 acc3 = {0.f, 0.f, 0.f, 0.f};

  f32x4 ca0 = *(const f32x4*)ap;
  f32x4 ca1 = *(const f32x4*)(ap + 4);
  s16x8 cb0 = *(const s16x8*)bp0;
  s16x8 cb1 = *(const s16x8*)bp1;
  s16x8 cb2 = *(const s16x8*)bp2;
  s16x8 cb3 = *(const s16x8*)bp3;

  for (int s = 0; s < 127; ++s) {
    ap += 32; bp0 += 32; bp1 += 32; bp2 += 32; bp3 += 32;
    f32x4 na0 = *(const f32x4*)ap;
    f32x4 na1 = *(const f32x4*)(ap + 4);
    s16x8 nb0 = *(const s16x8*)bp0;
    s16x8 nb1 = *(const s16x8*)bp1;
    s16x8 nb2 = *(const s16x8*)bp2;
    s16x8 nb3 = *(const s16x8*)bp3;

    s16x8 af = cvt8(ca0, ca1);
    acc0 = __builtin_amdgcn_mfma_f32_16x16x32_bf16(af, cb0, acc0, 0, 0, 0);
    acc1 = __builtin_amdgcn_mfma_f32_16x16x32_bf16(af, cb1, acc1, 0, 0, 0);
    acc2 = __builtin_amdgcn_mfma_f32_16x16x32_bf16(af, cb2, acc2, 0, 0, 0);
    acc3 = __builtin_amdgcn_mfma_f32_16x16x32_bf16(af, cb3, acc3, 0, 0, 0);

    ca0 = na0; ca1 = na1;
    cb0 = nb0; cb1 = nb1; cb2 = nb2; cb3 = nb3;
  }
  {
    s16x8 af = cvt8(ca0, ca1);
    acc0 = __builtin_amdgcn_mfma_f32_16x16x32_bf16(af, cb0, acc0, 0, 0, 0);
    acc1 = __builtin_amdgcn_mfma_f32_16x16x32_bf16(af, cb1, acc1, 0, 0, 0);
    acc2 = __builtin_amdgcn_mfma_f32_16x16x32_bf16(af, cb2, acc2, 0, 0, 0);
    acc3 = __builtin_amdgcn_mfma_f32_16x16x32_bf16(af, cb3, acc3, 0, 0, 0);
  }

  // D layout: col = lane&15 (+16*f), row = (lane>>4)*4 + reg  [m89-verified]
  int zr = (blockIdx.x << 6) + (w << 4) + ((lane >> 4) << 2);
  float* zp = Z + (size_t)zr * 64 + l15;
  #pragma unroll
  for (int r = 0; r < 4; ++r) {
    atomicAdd(zp + (size_t)r * 64 + 0, acc0[r]);
    atomicAdd(zp + (size_t)r * 64 + 16, acc1[r]);
    atomicAdd(zp + (size_t)r * 64 + 32, acc2[r]);
    atomicAdd(zp + (size_t)r * 64 + 48, acc3[r]);
  }
}

// mid epilogue: x = relu(Z*rw1[reg]+rb1[reg]); Z = x@W2 (in-place); Bt = (x@L2)^T bf16
__global__ __launch_bounds__(256) void k_mid(
    float* __restrict__ Z, const int* __restrict__ reg,
    const float* __restrict__ rw1, const float* __restrict__ rb1,
    const float* __restrict__ W2, const float* __restrict__ L2,
    unsigned short* __restrict__ Bt) {
  __shared__ float Ws[4096], Ls[4096], xs[16 * 64];
  int tid = threadIdx.x;
  for (int i = tid; i < 4096; i += 256) { Ws[i] = W2[i]; Ls[i] = L2[i]; }
  int r = tid >> 6, c = tid & 63;
  int i0 = blockIdx.x << 4;
  #pragma unroll
  for (int m = 0; m < 4; ++m) {
    int i = i0 + r + 4 * m;
    int ri = reg[i];
    float z = Z[(size_t)i * 64 + c];
    float x = z * rw1[ri * 64 + c] + rb1[ri * 64 + c];
    xs[(r + 4 * m) * 64 + c] = fmaxf(x, 0.f);
  }
  __syncthreads();
  float a1[4] = {0.f, 0.f, 0.f, 0.f};
  float a2[4] = {0.f, 0.f, 0.f, 0.f};
  #pragma unroll 8
  for (int k = 0; k < 64; ++k) {
    float wv = Ws[k * 64 + c];
    float lv = Ls[k * 64 + c];
    #pragma unroll
    for (int m = 0; m < 4; ++m) {
      float xv = xs[(r + 4 * m) * 64 + k];
      a1[m] += xv * wv;
      a2[m] += xv * lv;
    }
  }
  #pragma unroll
  for (int m = 0; m < 4; ++m) {
    int i = i0 + r + 4 * m;
    Z[(size_t)i * 64 + c] = a1[m];
    Bt[(size_t)c * BTS + i] = f2bf(a2[m]);
  }
}

// out epilogue: x2 = relu(Z*rw2[reg]+rb2[reg]); out = x2 @ Wout^T + bout
__global__ __launch_bounds__(256) void k_out(
    const float* __restrict__ Z, const int* __restrict__ reg,
    const float* __restrict__ rw2, const float* __restrict__ rb2,
    const float* __restrict__ Wout, const float* __restrict__ bout,
    float* __restrict__ out) {
  __shared__ float xs[16 * 64];
  int tid = threadIdx.x;
  int r = tid >> 6, c = tid & 63;
  int i0 = blockIdx.x << 4;
  #pragma unroll
  for (int m = 0; m < 4; ++m) {
    int i = i0 + r + 4 * m;
    int ri = reg[i];
    float z = Z[(size_t)i * 64 + c];
    float x = z * rw2[ri * 64 + c] + rb2[ri * 64 + c];
    xs[(r + 4 * m) * 64 + c] = fmaxf(x, 0.f);
  }
  __syncthreads();
  if (c < 8) {
    #pragma unroll
    for (int m = 0; m < 4; ++m) {
      int i = i0 + r + 4 * m;
      float a = bout[c];
      #pragma unroll 8
      for (int k = 0; k < 64; ++k) a += xs[(r + 4 * m) * 64 + k] * Wout[c * 64 + k];
      out[(size_t)i * 8 + c] = a;
    }
  }
}

extern "C" void kernel_launch(void* const* d_in, const int* in_sizes, int n_in,
                              void* d_out, int out_size, void* d_ws, size_t ws_size,
                              hipStream_t stream) {
  const float* h    = (const float*)d_in[0];
  const float* adj  = (const float*)d_in[1];
  const int*   reg  = (const int*)d_in[2];
  const float* W1   = (const float*)d_in[3];
  const float* L1   = (const float*)d_in[4];
  const float* rw1  = (const float*)d_in[5];
  const float* rb1  = (const float*)d_in[6];
  const float* W2   = (const float*)d_in[7];
  const float* L2   = (const float*)d_in[8];
  const float* rw2  = (const float*)d_in[9];
  const float* rb2  = (const float*)d_in[10];
  const float* Wout = (const float*)d_in[11];
  const float* bout = (const float*)d_in[12];
  float* out = (float*)d_out;

  float* Z = (float*)d_ws;                                          // 4 MB
  unsigned short* Bt = (unsigned short*)((char*)d_ws + (size_t)NV * DH * 4);  // ~2 MB padded

  k_prep<<<NV / 16, 256, 0, stream>>>(h, W1, L1, Z, Bt);
  k_adj<<<dim3(NV / 64, 4), 256, 0, stream>>>(adj, Bt, Z);
  k_mid<<<NV / 16, 256, 0, stream>>>(Z, reg, rw1, rb1, W2, L2, Bt);
  k_adj<<<dim3(NV / 64, 4), 256, 0, stream>>>(adj, Bt, Z);
  k_out<<<NV / 16, 256, 0, stream>>>(Z, reg, rw2, rb2, Wout, bout, out);
}

// Round 4
// 433.917 us; speedup vs baseline: 2.0512x; 1.8345x over previous
//
#include <hip/hip_runtime.h>
#include <stdint.h>

#define NV 16384
#define DH 64
#define BTS (NV + 64)     // Bt row stride (elements)
#define BK 256            // K-chunk size (columns per LDS stage)
#define LDST 264          // LDS row stride in ushorts (528B: bank-quad shift 1/row)
#define NCH 32            // chunks per block: 8192 / 256

typedef __attribute__((ext_vector_type(4))) float f32x4;
typedef __attribute__((ext_vector_type(8))) short s16x8;

static __device__ __forceinline__ unsigned short f2bf(float f) {
  union { float f; unsigned u; } x; x.f = f;
  unsigned r = x.u + 0x7fffu + ((x.u >> 16) & 1u);
  return (unsigned short)(r >> 16);
}

static __device__ __forceinline__ s16x8 cvt8(f32x4 a, f32x4 b) {
  s16x8 r;
  r[0] = (short)f2bf(a[0]); r[1] = (short)f2bf(a[1]);
  r[2] = (short)f2bf(a[2]); r[3] = (short)f2bf(a[3]);
  r[4] = (short)f2bf(b[0]); r[5] = (short)f2bf(b[1]);
  r[6] = (short)f2bf(b[2]); r[7] = (short)f2bf(b[3]);
  return r;
}

// prep: Z[i][c] = (h@W1)[i][c] fp32 ; Bt[c][i] = bf16((h@L1)[i][c])
__global__ __launch_bounds__(256) void k_prep(
    const float* __restrict__ h, const float* __restrict__ W1,
    const float* __restrict__ L1, float* __restrict__ Z,
    unsigned short* __restrict__ Bt) {
  __shared__ float Ws[4096], Ls[4096], hs[16 * 64];
  int tid = threadIdx.x;
  for (int i = tid; i < 4096; i += 256) { Ws[i] = W1[i]; Ls[i] = L1[i]; }
  int r = tid >> 6, c = tid & 63;
  int i0 = blockIdx.x << 4;
  #pragma unroll
  for (int m = 0; m < 4; ++m)
    hs[(r + 4 * m) * 64 + c] = h[(size_t)(i0 + r + 4 * m) * 64 + c];
  __syncthreads();
  float a1[4] = {0.f, 0.f, 0.f, 0.f};
  float a2[4] = {0.f, 0.f, 0.f, 0.f};
  #pragma unroll 8
  for (int k = 0; k < 64; ++k) {
    float wv = Ws[k * 64 + c];
    float lv = Ls[k * 64 + c];
    #pragma unroll
    for (int m = 0; m < 4; ++m) {
      float hv = hs[(r + 4 * m) * 64 + k];
      a1[m] += hv * wv;
      a2[m] += hv * lv;
    }
  }
  #pragma unroll
  for (int m = 0; m < 4; ++m) {
    int i = i0 + r + 4 * m;
    Z[(size_t)i * 64 + c] = a1[m];
    Bt[(size_t)c * BTS + i] = f2bf(a2[m]);
  }
}

// big: P[y] = adj[:, yhalf] @ B[yhalf, :]   (pure stores, no atomics)
// Bt chunks staged to LDS (double-buffered) so Bt hits L2/LDS instead of
// being re-fetched from HBM by every block; adj register-streamed depth-4.
__global__ __launch_bounds__(256, 2) void k_adj(
    const float* __restrict__ adj, const unsigned short* __restrict__ Bt,
    float* __restrict__ P) {
  __shared__ __align__(16) unsigned short Blds[2 * 64 * LDST];
  const int tid = threadIdx.x;
  const int lane = tid & 63;
  const int w = tid >> 6;
  const int l15 = lane & 15;
  const int kgrp = lane >> 4;                 // 0..3
  const int xb = blockIdx.x;
  const int yb = blockIdx.y;
  const int row = (xb << 6) + (w << 4) + l15;
  const int kbase = yb << 13;                 // 8192 per half

  // staging map: thread -> (srow base, 16B col unit); rows +0/16/32/48, seg 0/1
  const int srow = tid >> 4;                  // 0..15
  const int sc16 = tid & 15;
  const unsigned short* sbase = Bt + (size_t)srow * BTS + kbase + sc16 * 8;
  unsigned short* lbase = Blds + srow * LDST + sc16 * 8;

  const float* ap = adj + (size_t)row * NV + kbase + kgrp * 8;
  const int bofs0 = (l15 +  0) * LDST + kgrp * 8;
  const int bofs1 = (l15 + 16) * LDST + kgrp * 8;
  const int bofs2 = (l15 + 32) * LDST + kgrp * 8;
  const int bofs3 = (l15 + 48) * LDST + kgrp * 8;

  f32x4 sr0, sr1, sr2, sr3, sr4, sr5, sr6, sr7;
#define STAGE_LOAD(KC)                                                   \
  { const unsigned short* s_ = sbase + (KC);                             \
    sr0 = *(const f32x4*)(s_);                                           \
    sr1 = *(const f32x4*)(s_ + 128);                                     \
    sr2 = *(const f32x4*)(s_ + (size_t)16 * BTS);                        \
    sr3 = *(const f32x4*)(s_ + (size_t)16 * BTS + 128);                  \
    sr4 = *(const f32x4*)(s_ + (size_t)32 * BTS);                        \
    sr5 = *(const f32x4*)(s_ + (size_t)32 * BTS + 128);                  \
    sr6 = *(const f32x4*)(s_ + (size_t)48 * BTS);                        \
    sr7 = *(const f32x4*)(s_ + (size_t)48 * BTS + 128); }
#define STAGE_WRITE(BUF)                                                 \
  { unsigned short* d_ = lbase + (BUF) * (64 * LDST);                    \
    *(f32x4*)(d_) = sr0;                                                 \
    *(f32x4*)(d_ + 128) = sr1;                                           \
    *(f32x4*)(d_ + 16 * LDST) = sr2;                                     \
    *(f32x4*)(d_ + 16 * LDST + 128) = sr3;                               \
    *(f32x4*)(d_ + 32 * LDST) = sr4;                                     \
    *(f32x4*)(d_ + 32 * LDST + 128) = sr5;                               \
    *(f32x4*)(d_ + 48 * LDST) = sr6;                                     \
    *(f32x4*)(d_ + 48 * LDST + 128) = sr7; }

  f32x4 aj0a, aj0b, aj1a, aj1b, aj2a, aj2b, aj3a, aj3b;

  // prologue: stage chunk 0; prefetch adj iters 0..3
  STAGE_LOAD(0);
  aj0a = *(const f32x4*)(ap +   0); aj0b = *(const f32x4*)(ap +   4);
  aj1a = *(const f32x4*)(ap +  32); aj1b = *(const f32x4*)(ap +  36);
  aj2a = *(const f32x4*)(ap +  64); aj2b = *(const f32x4*)(ap +  68);
  aj3a = *(const f32x4*)(ap +  96); aj3b = *(const f32x4*)(ap + 100);
  STAGE_WRITE(0);
  __syncthreads();

  f32x4 acc0 = {0.f, 0.f, 0.f, 0.f};
  f32x4 acc1 = {0.f, 0.f, 0.f, 0.f};
  f32x4 acc2 = {0.f, 0.f, 0.f, 0.f};
  f32x4 acc3 = {0.f, 0.f, 0.f, 0.f};

#define ITER(II, AJA, AJB)                                               \
  {                                                                      \
    s16x8 af = cvt8(AJA, AJB);                                           \
    int ci = ((t << 3) + (II) + 4) & 255;                                \
    AJA = *(const f32x4*)(ap + (size_t)ci * 32);                         \
    AJB = *(const f32x4*)(ap + (size_t)ci * 32 + 4);                     \
    s16x8 cb0 = *(const s16x8*)(bb + bofs0 + (II) * 32);                 \
    s16x8 cb1 = *(const s16x8*)(bb + bofs1 + (II) * 32);                 \
    s16x8 cb2 = *(const s16x8*)(bb + bofs2 + (II) * 32);                 \
    s16x8 cb3 = *(const s16x8*)(bb + bofs3 + (II) * 32);                 \
    acc0 = __builtin_amdgcn_mfma_f32_16x16x32_bf16(af, cb0, acc0, 0, 0, 0); \
    acc1 = __builtin_amdgcn_mfma_f32_16x16x32_bf16(af, cb1, acc1, 0, 0, 0); \
    acc2 = __builtin_amdgcn_mfma_f32_16x16x32_bf16(af, cb2, acc2, 0, 0, 0); \
    acc3 = __builtin_amdgcn_mfma_f32_16x16x32_bf16(af, cb3, acc3, 0, 0, 0); \
  }

  for (int t = 0; t < NCH; ++t) {
    const unsigned short* bb = Blds + (t & 1) * (64 * LDST);
    if (t + 1 < NCH) STAGE_LOAD((t + 1) * BK);
    ITER(0, aj0a, aj0b)
    ITER(1, aj1a, aj1b)
    ITER(2, aj2a, aj2b)
    ITER(3, aj3a, aj3b)
    ITER(4, aj0a, aj0b)
    ITER(5, aj1a, aj1b)
    ITER(6, aj2a, aj2b)
    ITER(7, aj3a, aj3b)
    if (t + 1 < NCH) STAGE_WRITE((t + 1) & 1);
    __syncthreads();
  }

  // D layout: col = lane&15 (+16*f), row = (lane>>4)*4 + reg  [m89-verified]
  int zr = (xb << 6) + (w << 4) + (kgrp << 2);
  float* pp = P + (size_t)yb * NV * 64 + (size_t)zr * 64 + l15;
  #pragma unroll
  for (int r = 0; r < 4; ++r) {
    pp[(size_t)r * 64 +  0] = acc0[r];
    pp[(size_t)r * 64 + 16] = acc1[r];
    pp[(size_t)r * 64 + 32] = acc2[r];
    pp[(size_t)r * 64 + 48] = acc3[r];
  }
#undef STAGE_LOAD
#undef STAGE_WRITE
#undef ITER
}

// mid: x = relu((Z+P0+P1)*rw1[reg]+rb1[reg]); Z = x@W2; Bt = (x@L2)^T bf16
__global__ __launch_bounds__(256) void k_mid(
    float* __restrict__ Z, const float* __restrict__ P,
    const int* __restrict__ reg,
    const float* __restrict__ rw1, const float* __restrict__ rb1,
    const float* __restrict__ W2, const float* __restrict__ L2,
    unsigned short* __restrict__ Bt) {
  __shared__ float Ws[4096], Ls[4096], xs[16 * 64];
  int tid = threadIdx.x;
  for (int i = tid; i < 4096; i += 256) { Ws[i] = W2[i]; Ls[i] = L2[i]; }
  int r = tid >> 6, c = tid & 63;
  int i0 = blockIdx.x << 4;
  #pragma unroll
  for (int m = 0; m < 4; ++m) {
    int i = i0 + r + 4 * m;
    int ri = reg[i];
    size_t o = (size_t)i * 64 + c;
    float z = Z[o] + P[o] + P[(size_t)NV * 64 + o];
    float x = z * rw1[ri * 64 + c] + rb1[ri * 64 + c];
    xs[(r + 4 * m) * 64 + c] = fmaxf(x, 0.f);
  }
  __syncthreads();
  float a1[4] = {0.f, 0.f, 0.f, 0.f};
  float a2[4] = {0.f, 0.f, 0.f, 0.f};
  #pragma unroll 8
  for (int k = 0; k < 64; ++k) {
    float wv = Ws[k * 64 + c];
    float lv = Ls[k * 64 + c];
    #pragma unroll
    for (int m = 0; m < 4; ++m) {
      float xv = xs[(r + 4 * m) * 64 + k];
      a1[m] += xv * wv;
      a2[m] += xv * lv;
    }
  }
  #pragma unroll
  for (int m = 0; m < 4; ++m) {
    int i = i0 + r + 4 * m;
    Z[(size_t)i * 64 + c] = a1[m];
    Bt[(size_t)c * BTS + i] = f2bf(a2[m]);
  }
}

// out: x2 = relu((Z+P0+P1)*rw2[reg]+rb2[reg]); out = x2 @ Wout^T + bout
__global__ __launch_bounds__(256) void k_out(
    const float* __restrict__ Z, const float* __restrict__ P,
    const int* __restrict__ reg,
    const float* __restrict__ rw2, const float* __restrict__ rb2,
    const float* __restrict__ Wout, const float* __restrict__ bout,
    float* __restrict__ out) {
  __shared__ float xs[16 * 64];
  int tid = threadIdx.x;
  int r = tid >> 6, c = tid & 63;
  int i0 = blockIdx.x << 4;
  #pragma unroll
  for (int m = 0; m < 4; ++m) {
    int i = i0 + r + 4 * m;
    int ri = reg[i];
    size_t o = (size_t)i * 64 + c;
    float z = Z[o] + P[o] + P[(size_t)NV * 64 + o];
    float x = z * rw2[ri * 64 + c] + rb2[ri * 64 + c];
    xs[(r + 4 * m) * 64 + c] = fmaxf(x, 0.f);
  }
  __syncthreads();
  if (c < 8) {
    #pragma unroll
    for (int m = 0; m < 4; ++m) {
      int i = i0 + r + 4 * m;
      float a = bout[c];
      #pragma unroll 8
      for (int k = 0; k < 64; ++k) a += xs[(r + 4 * m) * 64 + k] * Wout[c * 64 + k];
      out[(size_t)i * 8 + c] = a;
    }
  }
}

extern "C" void kernel_launch(void* const* d_in, const int* in_sizes, int n_in,
                              void* d_out, int out_size, void* d_ws, size_t ws_size,
                              hipStream_t stream) {
  const float* h    = (const float*)d_in[0];
  const float* adj  = (const float*)d_in[1];
  const int*   reg  = (const int*)d_in[2];
  const float* W1   = (const float*)d_in[3];
  const float* L1   = (const float*)d_in[4];
  const float* rw1  = (const float*)d_in[5];
  const float* rb1  = (const float*)d_in[6];
  const float* W2   = (const float*)d_in[7];
  const float* L2   = (const float*)d_in[8];
  const float* rw2  = (const float*)d_in[9];
  const float* rb2  = (const float*)d_in[10];
  const float* Wout = (const float*)d_in[11];
  const float* bout = (const float*)d_in[12];
  float* out = (float*)d_out;

  float* Z = (float*)d_ws;                                                    // 4 MB @ 0
  unsigned short* Bt = (unsigned short*)((char*)d_ws + ((size_t)4 << 20));    // ~2.1 MB @ 4 MB
  float* P = (float*)((char*)d_ws + ((size_t)8 << 20));                       // 8 MB @ 8 MB

  k_prep<<<NV / 16, 256, 0, stream>>>(h, W1, L1, Z, Bt);
  k_adj<<<dim3(NV / 64, 2), 256, 0, stream>>>(adj, Bt, P);
  k_mid<<<NV / 16, 256, 0, stream>>>(Z, P, reg, rw1, rb1, W2, L2, Bt);
  k_adj<<<dim3(NV / 64, 2), 256, 0, stream>>>(adj, Bt, P);
  k_out<<<NV / 16, 256, 0, stream>>>(Z, P, reg, rw2, rb2, Wout, bout, out);
}